// Round 5
// baseline (17090.060 us; speedup 1.0000x reference)
//
#include <hip/hip_runtime.h>
#include <hip/hip_cooperative_groups.h>
#include <cstdint>
#include <cstddef>

namespace cg = cooperative_groups;

typedef unsigned short u16;
typedef __attribute__((ext_vector_type(8))) short short8;
typedef __attribute__((ext_vector_type(4))) short short4v;
typedef __attribute__((ext_vector_type(4))) float f32x4;

// B=512, T=64, D=16, H=1024 ; 4H=4096
#define NB 512
#define NT 64
#define ND 16
#define NH 1024
#define LDSBUF 12288  // u16 per buffer: A 64x64 (4096) + B 128x64 (8192)

__device__ __forceinline__ u16 f2bf(float x) {
  union { float f; unsigned u; } v; v.f = x;
  unsigned r = v.u + 0x7fffu + ((v.u >> 16) & 1u);
  return (u16)(r >> 16);
}
__device__ __forceinline__ float bf2f(u16 u) {
  union { float f; unsigned u; } v; v.u = ((unsigned)u) << 16;
  return v.f;
}
__device__ __forceinline__ float sigf(float x) { return 1.f / (1.f + __expf(-x)); }

__device__ __forceinline__ void glds16(const void* g, void* l) {
  __builtin_amdgcn_global_load_lds((const __attribute__((address_space(1))) void*)g,
                                   (__attribute__((address_space(3))) void*)l, 16, 0, 0);
}

// XOR swizzle: 16B-slot ^= (row & 7). Bijective within each 64-col (8-slot) chunk.
__device__ __forceinline__ int swz(int row, int col) {
  return ((((col >> 3) ^ (row & 7)) << 3) | (col & 7));
}

// n' = (h/16)*64 + gate*16 + (h%16)  ->  orig row = gate*1024 + h
__device__ __forceinline__ int inv_np(int np) {
  int hb = np >> 6, g = (np >> 4) & 3, hlo = np & 15;
  return g * 1024 + hb * 16 + hlo;
}

// ---------------- prep kernels (unchanged from R2/R3, proven) ----------------
__global__ void k_prep_big(const float* s0, const float* s1, const float* s2,
                           const float* s3, const float* s4, const float* s5, u16* dst) {
  for (unsigned q = blockIdx.x * 256 + threadIdx.x; q < (6u << 20); q += gridDim.x * 256) {
    int mat = q >> 20;
    int rem = q & ((1 << 20) - 1);
    int np = rem >> 8;
    int k = (rem & 255) * 4;
    int row = inv_np(np);
    const float* s = mat == 0 ? s0 : mat == 1 ? s1 : mat == 2 ? s2 : mat == 3 ? s3 : mat == 4 ? s4 : s5;
    float4 v = *(const float4*)(s + (size_t)row * NH + k);
    u16* d = dst + (size_t)mat * 4194304 + (size_t)np * NH + swz(np, k);
    d[0] = f2bf(v.x); d[1] = f2bf(v.y); d[2] = f2bf(v.z); d[3] = f2bf(v.w);
  }
}

__global__ void k_prep_small(const float* fwih0, const float* bwih0,
                             const float* fbi0, const float* fbh0, const float* fbi1, const float* fbh1,
                             const float* bbi0, const float* bbh0, const float* bbi1, const float* bbh1,
                             const float* outW,
                             u16* wih0p, float* biasb, u16* owbf) {
  int idx = blockIdx.x * 256 + threadIdx.x;
  if (idx < 524288) {
    int dir = idx >> 18;
    int r = idx & 262143;
    int np = r >> 6, d = r & 63;
    int row = inv_np(np);
    const float* s = dir ? bwih0 : fwih0;
    float v = (d < 16) ? s[row * 16 + d] : 0.f;
    wih0p[(size_t)dir * 262144 + (size_t)np * 64 + swz(np, d)] = f2bf(v);
  } else if (idx < 524288 + 16384) {
    int j = idx - 524288;
    int which = j >> 12;
    int np = j & 4095;
    int row = inv_np(np);
    const float* bi = which == 0 ? fbi0 : which == 1 ? fbi1 : which == 2 ? bbi0 : bbi1;
    const float* bh = which == 0 ? fbh0 : which == 1 ? fbh1 : which == 2 ? bbh0 : bbh1;
    biasb[which * 4096 + np] = bi[row] + bh[row];
  } else if (idx < 524288 + 16384 + 16384) {
    int j = idx - 524288 - 16384;
    owbf[j] = f2bf(outW[j]);
  }
}

__global__ void k_init(const float* fbi1, const float* fbh1, const float* bbi1, const float* bbh1,
                       float* c0, float* c1, u16* h0bf, u16* h1bf) {
  int idx = blockIdx.x * 256 + threadIdx.x;
  int dir = idx >> 19;
  int rem = idx & ((1 << 19) - 1);
  int b = rem >> 10, h = rem & 1023;
  const float* bi = dir ? bbi1 : fbi1;
  const float* bh = dir ? bbh1 : fbh1;
  float gi = bi[h] + bh[h];
  float gg = bi[2048 + h] + bh[2048 + h];
  float go = bi[3072 + h] + bh[3072 + h];
  float c = sigf(gi) * tanhf(gg);
  float hv = sigf(go) * tanhf(c);
  size_t o = (size_t)dir * 524288 + rem;
  c1[o] = c;
  h1bf[(size_t)(dir * 2) * 524288 + (size_t)b * NH + swz(b, h)] = f2bf(hv);
  c0[o] = 0.f;
  h0bf[(size_t)(dir * 2) * 524288 + rem] = 0;
}

// t=0 cc seed -> slice 0; other 63 slices zeroed by memset
__global__ __launch_bounds__(256) void k_cc0(const u16* h1f, const u16* h1b,
                                             const float* outW, float* partial) {
  int dir = blockIdx.y;
  int w = threadIdx.x >> 6, lane = threadIdx.x & 63;
  int b = blockIdx.x * 4 + w;
  const u16* hb = dir ? h1b : h1f;
  int key = b & 7;
  short8 ha = *(const short8*)(hb + (size_t)b * NH + ((lane * 2) ^ key) * 8);
  short8 hc = *(const short8*)(hb + (size_t)b * NH + ((lane * 2 + 1) ^ key) * 8);
  float hf[16];
#pragma unroll
  for (int j = 0; j < 8; ++j) { hf[j] = bf2f((u16)ha[j]); hf[8 + j] = bf2f((u16)hc[j]); }
  float sums[16];
#pragma unroll
  for (int d = 0; d < 16; ++d) {
    const float* wr = outW + (size_t)d * NH + lane * 16;
    float s = 0.f;
#pragma unroll
    for (int j = 0; j < 16; ++j) s += hf[j] * wr[j];
#pragma unroll
    for (int off = 32; off; off >>= 1) s += __shfl_xor(s, off);
    sums[d] = s;
  }
  if (lane == 0) {
    float* dst = partial + (size_t)dir * 524288 + (size_t)b * 16;
#pragma unroll
    for (int d = 0; d < 16; ++d) dst[d] = sums[d];
  }
}

// ================= shared phase bodies =================
struct StepCtx {
  u16* h0bf; u16* h1bf;
  const u16* wbig; const u16* wih0p;
  const float* biasb;
  float* c0; float* c1;
  float* partial;                 // [dir][64 slices][512][16] f32
  const float* values; const float* masks; const float* outb;
  const u16* owbf;
};

__device__ __forceinline__ void phase_g0(u16* SM, const StepCtx& a, int dir,
                                         int m_blk, int n_blk, int t, int p) {
  const int m0 = m_blk * 64, n0 = n_blk * 128;
  const int tid = threadIdx.x, w = tid >> 6, lane = tid & 63;
  const int srow = lane >> 3, scol = (lane & 7) * 8;
  const int wm = w >> 1, wn = w & 1;
  const int fr = lane & 15, fq = lane >> 4;
  const int key = fr & 7;
  const u16* h0_in = a.h0bf + (size_t)(dir * 2 + p) * 524288;
  u16* h0_out = a.h0bf + (size_t)(dir * 2 + 1 - p) * 524288;
  const u16* W00 = a.wbig + (size_t)(dir * 3 + 0) * 4194304;
  const u16* Wcc = a.wih0p + (size_t)dir * 262144;
  const float* bias0 = a.biasb + (size_t)dir * 2 * 4096;
  float* cs0 = a.c0 + (size_t)dir * 524288;

  int aoff[2][2], boff[4][2];
#pragma unroll
  for (int mi = 0; mi < 2; ++mi)
#pragma unroll
    for (int kk = 0; kk < 2; ++kk)
      aoff[mi][kk] = (wm * 32 + mi * 16 + fr) * 64 + ((fq + kk * 4) ^ key) * 8;
#pragma unroll
  for (int ni = 0; ni < 4; ++ni)
#pragma unroll
    for (int kk = 0; kk < 2; ++kk)
      boff[ni][kk] = 4096 + (wn * 64 + ni * 16 + fr) * 64 + ((fq + kk * 4) ^ key) * 8;

  f32x4 acc[2][4];
#pragma unroll
  for (int i = 0; i < 2; ++i)
#pragma unroll
    for (int j = 0; j < 4; ++j) acc[i][j] = f32x4{0.f, 0.f, 0.f, 0.f};

  // prologue: reduce 64 cc partial slices, apply mask, write chunk-0 A tile (swizzled) to buf0
  {
    const int rl = tid >> 2, q = tid & 3;
    const int grow = m0 + rl;
    const int d4 = q * 4;
    float4 ps = {0.f, 0.f, 0.f, 0.f};
    const float* pp = a.partial + (size_t)dir * 524288 + (size_t)grow * 16 + d4;
    for (int nb = 0; nb < 64; ++nb) {
      float4 v = *(const float4*)(pp + (size_t)nb * 8192);
      ps.x += v.x; ps.y += v.y; ps.z += v.z; ps.w += v.w;
    }
    int tt = dir ? (NT - 1 - t) : t;
    float4 x = *(const float4*)(a.values + ((size_t)grow * NT + tt) * ND + d4);
    float4 m = *(const float4*)(a.masks + ((size_t)grow * NT + tt) * ND + d4);
    float4 ob = *(const float4*)(a.outb + d4);
    short4v cc;
    cc[0] = (short)f2bf((1.f - m.x) * (ps.x + ob.x) + m.x * x.x);
    cc[1] = (short)f2bf((1.f - m.y) * (ps.y + ob.y) + m.y * x.y);
    cc[2] = (short)f2bf((1.f - m.z) * (ps.z + ob.z) + m.z * x.z);
    cc[3] = (short)f2bf((1.f - m.w) * (ps.w + ob.w) + m.w * x.w);
    int k2 = rl & 7;
    *(short4v*)(SM + rl * 64 + (((d4 >> 3) ^ k2) << 3) + (d4 & 7)) = cc;
    short8 z8 = {0, 0, 0, 0, 0, 0, 0, 0};
    *(short8*)(SM + rl * 64 + (((2 + q) ^ k2) << 3)) = z8;
    if (q < 2) *(short8*)(SM + rl * 64 + (((6 + q) ^ k2) << 3)) = z8;
    asm volatile("s_waitcnt vmcnt(0) lgkmcnt(0)" ::: "memory");
    __builtin_amdgcn_sched_barrier(0);
  }

  auto stage0 = [&](int c) {
    int buf = c; while (buf >= 3) buf -= 3;
    u16* lb = SM + buf * LDSBUF;
    if (c == 0) {
#pragma unroll
      for (int k = 0; k < 4; ++k)
        glds16(Wcc + (size_t)(n0 + w * 32 + k * 8 + srow) * 64 + scol,
               lb + 4096 + (w * 32 + k * 8) * 64);
      return;
    }
    int ci = c - 1;
    const u16* pa = h0_in + (size_t)ci * 64;
    const u16* pw = W00 + (size_t)ci * 64;
    glds16(pa + (size_t)(m0 + w * 16 + srow) * NH + scol, lb + (w * 16) * 64);
    glds16(pa + (size_t)(m0 + w * 16 + 8 + srow) * NH + scol, lb + (w * 16 + 8) * 64);
#pragma unroll
    for (int k = 0; k < 4; ++k)
      glds16(pw + (size_t)(n0 + w * 32 + k * 8 + srow) * NH + scol,
             lb + 4096 + (w * 32 + k * 8) * 64);
  };

  stage0(0); stage0(1);
  for (int c = 0; c < 17; ++c) {
    if (c + 2 < 17) { stage0(c + 2); asm volatile("s_waitcnt vmcnt(12)" ::: "memory"); }
    else if (c == 15) asm volatile("s_waitcnt vmcnt(6)" ::: "memory");
    else asm volatile("s_waitcnt vmcnt(0)" ::: "memory");
    __builtin_amdgcn_s_barrier();
    __builtin_amdgcn_sched_barrier(0);
    int buf = c; while (buf >= 3) buf -= 3;
    const u16* base = SM + buf * LDSBUF;
    short8 af[2][2], bb[4][2];
#pragma unroll
    for (int kk = 0; kk < 2; ++kk) {
#pragma unroll
      for (int mi = 0; mi < 2; ++mi) af[mi][kk] = *(const short8*)(base + aoff[mi][kk]);
#pragma unroll
      for (int ni = 0; ni < 4; ++ni) bb[ni][kk] = *(const short8*)(base + boff[ni][kk]);
    }
#pragma unroll
    for (int kk = 0; kk < 2; ++kk)
#pragma unroll
      for (int mi = 0; mi < 2; ++mi)
#pragma unroll
        for (int ni = 0; ni < 4; ++ni)
          acc[mi][ni] = __builtin_amdgcn_mfma_f32_16x16x32_bf16(af[mi][kk], bb[ni][kk], acc[mi][ni], 0, 0, 0);
    __builtin_amdgcn_sched_barrier(0);
    __builtin_amdgcn_s_barrier();
  }

  const int hg = ((n0 + wn * 64) >> 2) + fr;
  const float b0 = bias0[n0 + wn * 64 + fr];
  const float b1 = bias0[n0 + wn * 64 + 16 + fr];
  const float b2 = bias0[n0 + wn * 64 + 32 + fr];
  const float b3 = bias0[n0 + wn * 64 + 48 + fr];
#pragma unroll
  for (int mi = 0; mi < 2; ++mi)
#pragma unroll
    for (int r = 0; r < 4; ++r) {
      int row = m0 + wm * 32 + mi * 16 + fq * 4 + r;
      size_t sidx = (size_t)row * NH + hg;
      float iv = acc[mi][0][r] + b0;
      float fv = acc[mi][1][r] + b1;
      float gv = acc[mi][2][r] + b2;
      float ov = acc[mi][3][r] + b3;
      float cp = cs0[sidx];
      float c2 = sigf(fv) * cp + sigf(iv) * tanhf(gv);
      float hvv = sigf(ov) * tanhf(c2);
      cs0[sidx] = c2;
      h0_out[(size_t)row * NH + swz(row, hg)] = f2bf(hvv);
    }
}

__device__ __forceinline__ void phase_g1(u16* SM, const StepCtx& a, int dir,
                                         int m_blk, int n_blk, int t, int p) {
  const int m0 = m_blk * 64, n0 = n_blk * 128;
  const int tid = threadIdx.x, w = tid >> 6, lane = tid & 63;
  const int srow = lane >> 3, scol = (lane & 7) * 8;
  const int wm = w >> 1, wn = w & 1;
  const int fr = lane & 15, fq = lane >> 4;
  const int key = fr & 7;
  const u16* h0_new = a.h0bf + (size_t)(dir * 2 + 1 - p) * 524288;
  const u16* h1_in = a.h1bf + (size_t)(dir * 2 + p) * 524288;
  u16* h1_out = a.h1bf + (size_t)(dir * 2 + 1 - p) * 524288;
  const u16* W10 = a.wbig + (size_t)(dir * 3 + 1) * 4194304;
  const u16* W11 = a.wbig + (size_t)(dir * 3 + 2) * 4194304;
  const float* bias1 = a.biasb + (size_t)(dir * 2 + 1) * 4096;
  float* cs1 = a.c1 + (size_t)dir * 524288;

  int aoff[2][2], boff[4][2];
#pragma unroll
  for (int mi = 0; mi < 2; ++mi)
#pragma unroll
    for (int kk = 0; kk < 2; ++kk)
      aoff[mi][kk] = (wm * 32 + mi * 16 + fr) * 64 + ((fq + kk * 4) ^ key) * 8;
#pragma unroll
  for (int ni = 0; ni < 4; ++ni)
#pragma unroll
    for (int kk = 0; kk < 2; ++kk)
      boff[ni][kk] = 4096 + (wn * 64 + ni * 16 + fr) * 64 + ((fq + kk * 4) ^ key) * 8;

  f32x4 acc[2][4];
#pragma unroll
  for (int i = 0; i < 2; ++i)
#pragma unroll
    for (int j = 0; j < 4; ++j) acc[i][j] = f32x4{0.f, 0.f, 0.f, 0.f};

  auto stage1 = [&](int c) {
    int buf = c; while (buf >= 3) buf -= 3;
    u16* lb = SM + buf * LDSBUF;
    const u16* pa; const u16* pw;
    if (c < 16) { pa = h0_new + (size_t)c * 64; pw = W10 + (size_t)c * 64; }
    else { pa = h1_in + (size_t)(c - 16) * 64; pw = W11 + (size_t)(c - 16) * 64; }
    glds16(pa + (size_t)(m0 + w * 16 + srow) * NH + scol, lb + (w * 16) * 64);
    glds16(pa + (size_t)(m0 + w * 16 + 8 + srow) * NH + scol, lb + (w * 16 + 8) * 64);
#pragma unroll
    for (int k = 0; k < 4; ++k)
      glds16(pw + (size_t)(n0 + w * 32 + k * 8 + srow) * NH + scol,
             lb + 4096 + (w * 32 + k * 8) * 64);
  };

  stage1(0); stage1(1);
  for (int c = 0; c < 32; ++c) {
    if (c + 2 < 32) { stage1(c + 2); asm volatile("s_waitcnt vmcnt(12)" ::: "memory"); }
    else if (c == 30) asm volatile("s_waitcnt vmcnt(6)" ::: "memory");
    else asm volatile("s_waitcnt vmcnt(0)" ::: "memory");
    __builtin_amdgcn_s_barrier();
    __builtin_amdgcn_sched_barrier(0);
    int buf = c; while (buf >= 3) buf -= 3;
    const u16* base = SM + buf * LDSBUF;
    short8 af[2][2], bb[4][2];
#pragma unroll
    for (int kk = 0; kk < 2; ++kk) {
#pragma unroll
      for (int mi = 0; mi < 2; ++mi) af[mi][kk] = *(const short8*)(base + aoff[mi][kk]);
#pragma unroll
      for (int ni = 0; ni < 4; ++ni) bb[ni][kk] = *(const short8*)(base + boff[ni][kk]);
    }
#pragma unroll
    for (int kk = 0; kk < 2; ++kk)
#pragma unroll
      for (int mi = 0; mi < 2; ++mi)
#pragma unroll
        for (int ni = 0; ni < 4; ++ni)
          acc[mi][ni] = __builtin_amdgcn_mfma_f32_16x16x32_bf16(af[mi][kk], bb[ni][kk], acc[mi][ni], 0, 0, 0);
    __builtin_amdgcn_sched_barrier(0);
    __builtin_amdgcn_s_barrier();
  }

  const int hb4 = (n0 + wn * 64) >> 2;
  const int hg = hb4 + fr;
  const float b0 = bias1[n0 + wn * 64 + fr];
  const float b1 = bias1[n0 + wn * 64 + 16 + fr];
  const float b2 = bias1[n0 + wn * 64 + 32 + fr];
  const float b3 = bias1[n0 + wn * 64 + 48 + fr];
  float hsv[2][4];
#pragma unroll
  for (int mi = 0; mi < 2; ++mi)
#pragma unroll
    for (int r = 0; r < 4; ++r) {
      int row = m0 + wm * 32 + mi * 16 + fq * 4 + r;
      size_t sidx = (size_t)row * NH + hg;
      float iv = acc[mi][0][r] + b0;
      float fv = acc[mi][1][r] + b1;
      float gv = acc[mi][2][r] + b2;
      float ov = acc[mi][3][r] + b3;
      float cp = cs1[sidx];
      float c2 = sigf(fv) * cp + sigf(iv) * tanhf(gv);
      float hvv = sigf(ov) * tanhf(c2);
      cs1[sidx] = c2;
      h1_out[(size_t)row * NH + swz(row, hg)] = f2bf(hvv);
      hsv[mi][r] = hvv;
    }

  // partial cc = h1_tile @ outW^T via transpose-MFMA; per (n_blk, wn) slice
  {
    u16* ts = SM + w * 512;  // per-wave 16x32 scratch (pipeline drained)
    *(short4v*)(ts + (lane >> 2) * 32 + 16 + (lane & 3) * 4) = short4v{0, 0, 0, 0};
    short8 afr = {0, 0, 0, 0, 0, 0, 0, 0};
    if (fq < 2) afr = *(const short8*)(a.owbf + (size_t)fr * NH + hb4 + fq * 8);
    float* pout = a.partial + ((size_t)(dir * 64 + n_blk * 2 + wn) * 512) * 16;
#pragma unroll
    for (int mi = 0; mi < 2; ++mi) {
#pragma unroll
      for (int r = 0; r < 4; ++r)
        *(ts + (fq * 4 + r) * 32 + fr) = f2bf(hsv[mi][r]);
      asm volatile("s_waitcnt lgkmcnt(0)" ::: "memory");
      __builtin_amdgcn_sched_barrier(0);
      short8 bfr2 = *(const short8*)(ts + fr * 32 + fq * 8);
      f32x4 pz = {0.f, 0.f, 0.f, 0.f};
      pz = __builtin_amdgcn_mfma_f32_16x16x32_bf16(afr, bfr2, pz, 0, 0, 0);
      int row = m0 + wm * 32 + mi * 16 + fr;
      float4 st = {pz[0], pz[1], pz[2], pz[3]};
      *(float4*)(pout + (size_t)row * 16 + fq * 4) = st;
      asm volatile("s_waitcnt lgkmcnt(0)" ::: "memory");
      __builtin_amdgcn_sched_barrier(0);
    }
  }
}

// ================= cooperative persistent kernel =================
__global__ __launch_bounds__(256, 2) void k_persist(StepCtx a) {
  cg::grid_group grid = cg::this_grid();
  __shared__ u16 SM[3 * LDSBUF];
  const int bid = blockIdx.x;
  const int n_blk = bid & 31, m_blk = (bid >> 5) & 7, dir = bid >> 8;
  for (int t = 0; t < NT; ++t) {
    const int p = t & 1;
    phase_g0(SM, a, dir, m_blk, n_blk, t, p);
    __threadfence();
    grid.sync();
    phase_g1(SM, a, dir, m_blk, n_blk, t, p);
    __threadfence();
    grid.sync();
  }
}

// ================= fallback per-step kernels =================
__global__ __launch_bounds__(256) void k_g0(StepCtx a, int t) {
  __shared__ u16 SM[3 * LDSBUF];
  phase_g0(SM, a, blockIdx.z, blockIdx.y, blockIdx.x, t, t & 1);
}
__global__ __launch_bounds__(256) void k_g1(StepCtx a, int t) {
  __shared__ u16 SM[3 * LDSBUF];
  phase_g1(SM, a, blockIdx.z, blockIdx.y, blockIdx.x, t, t & 1);
}

// ---------------- final outputs ----------------
__global__ void k_final(const u16* hf1, const u16* hb1, const float* values,
                        const float* masks, float* out) {
  int idx = blockIdx.x * 256 + threadIdx.x;
  int b = idx >> 10, j = idx & 1023;
  float hf = bf2f(hf1[(size_t)b * NH + swz(b, j)]);
  int jr = NH - 1 - j;
  float hb = bf2f(hb1[(size_t)b * NH + swz(b, jr)]);
  float hv = 0.5f * (hf + hb);
  float m = masks[idx];
  out[idx] = hv;
  out[524288 + idx] = hv;
  out[1048576 + idx] = hv * (1.f - m) + values[idx] * m;
}

extern "C" void kernel_launch(void* const* d_in, const int* in_sizes, int n_in,
                              void* d_out, int out_size, void* d_ws, size_t ws_size,
                              hipStream_t stream) {
  const float* values  = (const float*)d_in[0];
  const float* masks   = (const float*)d_in[1];
  const float* fw_Wih0 = (const float*)d_in[2];
  const float* fw_Whh0 = (const float*)d_in[3];
  const float* fw_bih0 = (const float*)d_in[4];
  const float* fw_bhh0 = (const float*)d_in[5];
  const float* fw_Wih1 = (const float*)d_in[6];
  const float* fw_Whh1 = (const float*)d_in[7];
  const float* fw_bih1 = (const float*)d_in[8];
  const float* fw_bhh1 = (const float*)d_in[9];
  const float* bw_Wih0 = (const float*)d_in[10];
  const float* bw_Whh0 = (const float*)d_in[11];
  const float* bw_bih0 = (const float*)d_in[12];
  const float* bw_bhh0 = (const float*)d_in[13];
  const float* bw_Wih1 = (const float*)d_in[14];
  const float* bw_Whh1 = (const float*)d_in[15];
  const float* bw_bih1 = (const float*)d_in[16];
  const float* bw_bhh1 = (const float*)d_in[17];
  const float* out_W   = (const float*)d_in[18];
  const float* out_b   = (const float*)d_in[19];

  char* ws = (char*)d_ws;
  u16* wbig    = (u16*)ws;                    // 6 x 4M u16
  u16* wih0p   = (u16*)(ws + 50331648);       // 2 x 4096x64
  float* biasb = (float*)(ws + 51380224);     // 4 x 4096
  u16* owbf    = (u16*)(ws + 51445760);       // 16x1024 bf16
  float* c0    = (float*)(ws + 51478528);     // 2 x 512x1024 f32
  float* c1    = (float*)(ws + 55672832);
  u16* h0bf    = (u16*)(ws + 59867136);       // [dir][pp] x 512x1024 bf16 swizzled
  u16* h1bf    = (u16*)(ws + 64061440);
  float* partial = (float*)(ws + 68255744);   // [dir][64][512][16] f32 = 4 MB
  if (ws_size < 72450048) return;

  k_prep_big<<<4096, 256, 0, stream>>>(fw_Whh0, fw_Wih1, fw_Whh1, bw_Whh0, bw_Wih1, bw_Whh1, wbig);
  k_prep_small<<<2176, 256, 0, stream>>>(fw_Wih0, bw_Wih0, fw_bih0, fw_bhh0, fw_bih1, fw_bhh1,
                                         bw_bih0, bw_bhh0, bw_bih1, bw_bhh1, out_W,
                                         wih0p, biasb, owbf);
  k_init<<<4096, 256, 0, stream>>>(fw_bih1, fw_bhh1, bw_bih1, bw_bhh1, c0, c1, h0bf, h1bf);
  hipMemsetAsync(partial, 0, 4194304, stream);
  k_cc0<<<dim3(128, 2), 256, 0, stream>>>(h1bf, h1bf + (size_t)2 * 524288, out_W, partial);

  StepCtx sc;
  sc.h0bf = h0bf; sc.h1bf = h1bf;
  sc.wbig = wbig; sc.wih0p = wih0p;
  sc.biasb = biasb; sc.c0 = c0; sc.c1 = c1;
  sc.partial = partial;
  sc.values = values; sc.masks = masks; sc.outb = out_b;
  sc.owbf = owbf;

  void* kargs[] = {(void*)&sc};
  hipError_t e = hipLaunchCooperativeKernel((const void*)k_persist, dim3(512), dim3(256),
                                            kargs, 0, stream);
  if (e != hipSuccess) {
    // fallback: per-step dispatches (identical math, dispatch-boundary syncs)
    for (int t = 0; t < NT; ++t) {
      k_g0<<<dim3(32, 8, 2), 256, 0, stream>>>(sc, t);
      k_g1<<<dim3(32, 8, 2), 256, 0, stream>>>(sc, t);
    }
  }

  // after t=63: p=1, final h1 in buffer (1-p)=0
  k_final<<<2048, 256, 0, stream>>>(h1bf, h1bf + (size_t)2 * 524288, values, masks, (float*)d_out);
}

// Round 6
// 3177.994 us; speedup vs baseline: 5.3776x; 5.3776x over previous
//
#include <hip/hip_runtime.h>
#include <cstdint>
#include <cstddef>

typedef unsigned short u16;
typedef __attribute__((ext_vector_type(8))) short short8;
typedef __attribute__((ext_vector_type(4))) short short4v;
typedef __attribute__((ext_vector_type(4))) float f32x4;

// B=512, T=64, D=16, H=1024 ; 4H=4096
#define NB 512
#define NT 64
#define ND 16
#define NH 1024
#define LDSBUF 12288  // u16 per buffer: A 64x64 (4096) + B 128x64 (8192)

__device__ __forceinline__ u16 f2bf(float x) {
  union { float f; unsigned u; } v; v.f = x;
  unsigned r = v.u + 0x7fffu + ((v.u >> 16) & 1u);
  return (u16)(r >> 16);
}
__device__ __forceinline__ float bf2f(u16 u) {
  union { float f; unsigned u; } v; v.u = ((unsigned)u) << 16;
  return v.f;
}
__device__ __forceinline__ float sigf(float x) { return 1.f / (1.f + __expf(-x)); }

__device__ __forceinline__ void glds16(const void* g, void* l) {
  __builtin_amdgcn_global_load_lds((const __attribute__((address_space(1))) void*)g,
                                   (__attribute__((address_space(3))) void*)l, 16, 0, 0);
}

// XOR swizzle: 16B-slot ^= (row & 7). Bijective within each 64-col (8-slot) chunk.
__device__ __forceinline__ int swz(int row, int col) {
  return ((((col >> 3) ^ (row & 7)) << 3) | (col & 7));
}

// n' = (h/16)*64 + gate*16 + (h%16)  ->  orig row = gate*1024 + h
__device__ __forceinline__ int inv_np(int np) {
  int hb = np >> 6, g = (np >> 4) & 3, hlo = np & 15;
  return g * 1024 + hb * 16 + hlo;
}

// ---------------- prep kernels (proven) ----------------
__global__ void k_prep_big(const float* s0, const float* s1, const float* s2,
                           const float* s3, const float* s4, const float* s5, u16* dst) {
  for (unsigned q = blockIdx.x * 256 + threadIdx.x; q < (6u << 20); q += gridDim.x * 256) {
    int mat = q >> 20;
    int rem = q & ((1 << 20) - 1);
    int np = rem >> 8;
    int k = (rem & 255) * 4;
    int row = inv_np(np);
    const float* s = mat == 0 ? s0 : mat == 1 ? s1 : mat == 2 ? s2 : mat == 3 ? s3 : mat == 4 ? s4 : s5;
    float4 v = *(const float4*)(s + (size_t)row * NH + k);
    u16* d = dst + (size_t)mat * 4194304 + (size_t)np * NH + swz(np, k);
    d[0] = f2bf(v.x); d[1] = f2bf(v.y); d[2] = f2bf(v.z); d[3] = f2bf(v.w);
  }
}

__global__ void k_prep_small(const float* fwih0, const float* bwih0,
                             const float* fbi0, const float* fbh0, const float* fbi1, const float* fbh1,
                             const float* bbi0, const float* bbh0, const float* bbi1, const float* bbh1,
                             const float* outW,
                             u16* wih0p, float* biasb, u16* owbf) {
  int idx = blockIdx.x * 256 + threadIdx.x;
  if (idx < 524288) {
    int dir = idx >> 18;
    int r = idx & 262143;
    int np = r >> 6, d = r & 63;
    int row = inv_np(np);
    const float* s = dir ? bwih0 : fwih0;
    float v = (d < 16) ? s[row * 16 + d] : 0.f;
    wih0p[(size_t)dir * 262144 + (size_t)np * 64 + swz(np, d)] = f2bf(v);
  } else if (idx < 524288 + 16384) {
    int j = idx - 524288;
    int which = j >> 12;
    int np = j & 4095;
    int row = inv_np(np);
    const float* bi = which == 0 ? fbi0 : which == 1 ? fbi1 : which == 2 ? bbi0 : bbi1;
    const float* bh = which == 0 ? fbh0 : which == 1 ? fbh1 : which == 2 ? bbh0 : bbh1;
    biasb[which * 4096 + np] = bi[row] + bh[row];
  } else if (idx < 524288 + 16384 + 16384) {
    int j = idx - 524288 - 16384;
    owbf[j] = f2bf(outW[j]);
  }
}

__global__ void k_init(const float* fbi1, const float* fbh1, const float* bbi1, const float* bbh1,
                       float* c0, float* c1, u16* h0bf, u16* h1bf) {
  int idx = blockIdx.x * 256 + threadIdx.x;
  int dir = idx >> 19;
  int rem = idx & ((1 << 19) - 1);
  int b = rem >> 10, h = rem & 1023;
  const float* bi = dir ? bbi1 : fbi1;
  const float* bh = dir ? bbh1 : fbh1;
  float gi = bi[h] + bh[h];
  float gg = bi[2048 + h] + bh[2048 + h];
  float go = bi[3072 + h] + bh[3072 + h];
  float c = sigf(gi) * tanhf(gg);
  float hv = sigf(go) * tanhf(c);
  size_t o = (size_t)dir * 524288 + rem;
  c1[o] = c;
  h1bf[(size_t)(dir * 2) * 524288 + (size_t)b * NH + swz(b, h)] = f2bf(hv);
  c0[o] = 0.f;
  h0bf[(size_t)(dir * 2) * 524288 + rem] = 0;
}

// t=0 cc seed -> slice 0; other 63 slices zeroed by memset
__global__ __launch_bounds__(256) void k_cc0(const u16* h1f, const u16* h1b,
                                             const float* outW, float* partial) {
  int dir = blockIdx.y;
  int w = threadIdx.x >> 6, lane = threadIdx.x & 63;
  int b = blockIdx.x * 4 + w;
  const u16* hb = dir ? h1b : h1f;
  int key = b & 7;
  short8 ha = *(const short8*)(hb + (size_t)b * NH + ((lane * 2) ^ key) * 8);
  short8 hc = *(const short8*)(hb + (size_t)b * NH + ((lane * 2 + 1) ^ key) * 8);
  float hf[16];
#pragma unroll
  for (int j = 0; j < 8; ++j) { hf[j] = bf2f((u16)ha[j]); hf[8 + j] = bf2f((u16)hc[j]); }
  float sums[16];
#pragma unroll
  for (int d = 0; d < 16; ++d) {
    const float* wr = outW + (size_t)d * NH + lane * 16;
    float s = 0.f;
#pragma unroll
    for (int j = 0; j < 16; ++j) s += hf[j] * wr[j];
#pragma unroll
    for (int off = 32; off; off >>= 1) s += __shfl_xor(s, off);
    sums[d] = s;
  }
  if (lane == 0) {
    float* dst = partial + (size_t)dir * 524288 + (size_t)b * 16;
#pragma unroll
    for (int d = 0; d < 16; ++d) dst[d] = sums[d];
  }
}

// ================= shared phase bodies =================
struct StepCtx {
  u16* h0bf; u16* h1bf;
  const u16* wbig; const u16* wih0p;
  const float* biasb;
  float* c0; float* c1;
  float* partial;                 // [dir][64 slices][512][16] f32
  const float* values; const float* masks; const float* outb;
  const u16* owbf;
};

__device__ __forceinline__ void phase_g0(u16* SM, const StepCtx& a, int dir,
                                         int m_blk, int n_blk, int t, int p) {
  const int m0 = m_blk * 64, n0 = n_blk * 128;
  const int tid = threadIdx.x, w = tid >> 6, lane = tid & 63;
  const int srow = lane >> 3, scol = (lane & 7) * 8;
  const int wm = w >> 1, wn = w & 1;
  const int fr = lane & 15, fq = lane >> 4;
  const int key = fr & 7;
  const u16* h0_in = a.h0bf + (size_t)(dir * 2 + p) * 524288;
  u16* h0_out = a.h0bf + (size_t)(dir * 2 + 1 - p) * 524288;
  const u16* W00 = a.wbig + (size_t)(dir * 3 + 0) * 4194304;
  const u16* Wcc = a.wih0p + (size_t)dir * 262144;
  const float* bias0 = a.biasb + (size_t)dir * 2 * 4096;
  float* cs0 = a.c0 + (size_t)dir * 524288;

  int aoff[2][2], boff[4][2];
#pragma unroll
  for (int mi = 0; mi < 2; ++mi)
#pragma unroll
    for (int kk = 0; kk < 2; ++kk)
      aoff[mi][kk] = (wm * 32 + mi * 16 + fr) * 64 + ((fq + kk * 4) ^ key) * 8;
#pragma unroll
  for (int ni = 0; ni < 4; ++ni)
#pragma unroll
    for (int kk = 0; kk < 2; ++kk)
      boff[ni][kk] = 4096 + (wn * 64 + ni * 16 + fr) * 64 + ((fq + kk * 4) ^ key) * 8;

  f32x4 acc[2][4];
#pragma unroll
  for (int i = 0; i < 2; ++i)
#pragma unroll
    for (int j = 0; j < 4; ++j) acc[i][j] = f32x4{0.f, 0.f, 0.f, 0.f};

  // prologue: reduce 64 cc partial slices, apply mask, write chunk-0 A tile (swizzled) to buf0
  {
    const int rl = tid >> 2, q = tid & 3;
    const int grow = m0 + rl;
    const int d4 = q * 4;
    float4 ps = {0.f, 0.f, 0.f, 0.f};
    const float* pp = a.partial + (size_t)dir * 524288 + (size_t)grow * 16 + d4;
    for (int nb = 0; nb < 64; ++nb) {
      float4 v = *(const float4*)(pp + (size_t)nb * 8192);
      ps.x += v.x; ps.y += v.y; ps.z += v.z; ps.w += v.w;
    }
    int tt = dir ? (NT - 1 - t) : t;
    float4 x = *(const float4*)(a.values + ((size_t)grow * NT + tt) * ND + d4);
    float4 m = *(const float4*)(a.masks + ((size_t)grow * NT + tt) * ND + d4);
    float4 ob = *(const float4*)(a.outb + d4);
    short4v cc;
    cc[0] = (short)f2bf((1.f - m.x) * (ps.x + ob.x) + m.x * x.x);
    cc[1] = (short)f2bf((1.f - m.y) * (ps.y + ob.y) + m.y * x.y);
    cc[2] = (short)f2bf((1.f - m.z) * (ps.z + ob.z) + m.z * x.z);
    cc[3] = (short)f2bf((1.f - m.w) * (ps.w + ob.w) + m.w * x.w);
    int k2 = rl & 7;
    *(short4v*)(SM + rl * 64 + (((d4 >> 3) ^ k2) << 3) + (d4 & 7)) = cc;
    short8 z8 = {0, 0, 0, 0, 0, 0, 0, 0};
    *(short8*)(SM + rl * 64 + (((2 + q) ^ k2) << 3)) = z8;
    if (q < 2) *(short8*)(SM + rl * 64 + (((6 + q) ^ k2) << 3)) = z8;
    // prologue global loads drain via data use; only LDS writes need ordering pre-barrier
    asm volatile("s_waitcnt lgkmcnt(0)" ::: "memory");
    __builtin_amdgcn_sched_barrier(0);
  }

  auto stage0 = [&](int c) {
    int buf = c; while (buf >= 3) buf -= 3;
    u16* lb = SM + buf * LDSBUF;
    if (c == 0) {
#pragma unroll
      for (int k = 0; k < 4; ++k)
        glds16(Wcc + (size_t)(n0 + w * 32 + k * 8 + srow) * 64 + scol,
               lb + 4096 + (w * 32 + k * 8) * 64);
      return;
    }
    int ci = c - 1;
    const u16* pa = h0_in + (size_t)ci * 64;
    const u16* pw = W00 + (size_t)ci * 64;
    glds16(pa + (size_t)(m0 + w * 16 + srow) * NH + scol, lb + (w * 16) * 64);
    glds16(pa + (size_t)(m0 + w * 16 + 8 + srow) * NH + scol, lb + (w * 16 + 8) * 64);
#pragma unroll
    for (int k = 0; k < 4; ++k)
      glds16(pw + (size_t)(n0 + w * 32 + k * 8 + srow) * NH + scol,
             lb + 4096 + (w * 32 + k * 8) * 64);
  };

  stage0(0); stage0(1);
  // single barrier per chunk: wait(c) -> barrier -> stage(c+2) -> reads+MFMA
  for (int c = 0; c < 17; ++c) {
    if (c == 16) asm volatile("s_waitcnt vmcnt(0)" ::: "memory");
    else         asm volatile("s_waitcnt vmcnt(6)" ::: "memory");
    __builtin_amdgcn_s_barrier();
    __builtin_amdgcn_sched_barrier(0);
    if (c + 2 < 17) stage0(c + 2);
    int buf = c; while (buf >= 3) buf -= 3;
    const u16* base = SM + buf * LDSBUF;
    short8 af[2][2], bb[4][2];
#pragma unroll
    for (int kk = 0; kk < 2; ++kk) {
#pragma unroll
      for (int mi = 0; mi < 2; ++mi) af[mi][kk] = *(const short8*)(base + aoff[mi][kk]);
#pragma unroll
      for (int ni = 0; ni < 4; ++ni) bb[ni][kk] = *(const short8*)(base + boff[ni][kk]);
    }
#pragma unroll
    for (int kk = 0; kk < 2; ++kk)
#pragma unroll
      for (int mi = 0; mi < 2; ++mi)
#pragma unroll
        for (int ni = 0; ni < 4; ++ni)
          acc[mi][ni] = __builtin_amdgcn_mfma_f32_16x16x32_bf16(af[mi][kk], bb[ni][kk], acc[mi][ni], 0, 0, 0);
  }

  const int hg = ((n0 + wn * 64) >> 2) + fr;
  const float b0 = bias0[n0 + wn * 64 + fr];
  const float b1 = bias0[n0 + wn * 64 + 16 + fr];
  const float b2 = bias0[n0 + wn * 64 + 32 + fr];
  const float b3 = bias0[n0 + wn * 64 + 48 + fr];
#pragma unroll
  for (int mi = 0; mi < 2; ++mi)
#pragma unroll
    for (int r = 0; r < 4; ++r) {
      int row = m0 + wm * 32 + mi * 16 + fq * 4 + r;
      size_t sidx = (size_t)row * NH + hg;
      float iv = acc[mi][0][r] + b0;
      float fv = acc[mi][1][r] + b1;
      float gv = acc[mi][2][r] + b2;
      float ov = acc[mi][3][r] + b3;
      float cp = cs0[sidx];
      float c2 = sigf(fv) * cp + sigf(iv) * tanhf(gv);
      float hvv = sigf(ov) * tanhf(c2);
      cs0[sidx] = c2;
      h0_out[(size_t)row * NH + swz(row, hg)] = f2bf(hvv);
    }
}

__device__ __forceinline__ void phase_g1(u16* SM, const StepCtx& a, int dir,
                                         int m_blk, int n_blk, int t, int p) {
  const int m0 = m_blk * 64, n0 = n_blk * 128;
  const int tid = threadIdx.x, w = tid >> 6, lane = tid & 63;
  const int srow = lane >> 3, scol = (lane & 7) * 8;
  const int wm = w >> 1, wn = w & 1;
  const int fr = lane & 15, fq = lane >> 4;
  const int key = fr & 7;
  const u16* h0_new = a.h0bf + (size_t)(dir * 2 + 1 - p) * 524288;
  const u16* h1_in = a.h1bf + (size_t)(dir * 2 + p) * 524288;
  u16* h1_out = a.h1bf + (size_t)(dir * 2 + 1 - p) * 524288;
  const u16* W10 = a.wbig + (size_t)(dir * 3 + 1) * 4194304;
  const u16* W11 = a.wbig + (size_t)(dir * 3 + 2) * 4194304;
  const float* bias1 = a.biasb + (size_t)(dir * 2 + 1) * 4096;
  float* cs1 = a.c1 + (size_t)dir * 524288;

  int aoff[2][2], boff[4][2];
#pragma unroll
  for (int mi = 0; mi < 2; ++mi)
#pragma unroll
    for (int kk = 0; kk < 2; ++kk)
      aoff[mi][kk] = (wm * 32 + mi * 16 + fr) * 64 + ((fq + kk * 4) ^ key) * 8;
#pragma unroll
  for (int ni = 0; ni < 4; ++ni)
#pragma unroll
    for (int kk = 0; kk < 2; ++kk)
      boff[ni][kk] = 4096 + (wn * 64 + ni * 16 + fr) * 64 + ((fq + kk * 4) ^ key) * 8;

  f32x4 acc[2][4];
#pragma unroll
  for (int i = 0; i < 2; ++i)
#pragma unroll
    for (int j = 0; j < 4; ++j) acc[i][j] = f32x4{0.f, 0.f, 0.f, 0.f};

  auto stage1 = [&](int c) {
    int buf = c; while (buf >= 3) buf -= 3;
    u16* lb = SM + buf * LDSBUF;
    const u16* pa; const u16* pw;
    if (c < 16) { pa = h0_new + (size_t)c * 64; pw = W10 + (size_t)c * 64; }
    else { pa = h1_in + (size_t)(c - 16) * 64; pw = W11 + (size_t)(c - 16) * 64; }
    glds16(pa + (size_t)(m0 + w * 16 + srow) * NH + scol, lb + (w * 16) * 64);
    glds16(pa + (size_t)(m0 + w * 16 + 8 + srow) * NH + scol, lb + (w * 16 + 8) * 64);
#pragma unroll
    for (int k = 0; k < 4; ++k)
      glds16(pw + (size_t)(n0 + w * 32 + k * 8 + srow) * NH + scol,
             lb + 4096 + (w * 32 + k * 8) * 64);
  };

  stage1(0); stage1(1);
  for (int c = 0; c < 32; ++c) {
    if (c == 31) asm volatile("s_waitcnt vmcnt(0)" ::: "memory");
    else         asm volatile("s_waitcnt vmcnt(6)" ::: "memory");
    __builtin_amdgcn_s_barrier();
    __builtin_amdgcn_sched_barrier(0);
    if (c + 2 < 32) stage1(c + 2);
    int buf = c; while (buf >= 3) buf -= 3;
    const u16* base = SM + buf * LDSBUF;
    short8 af[2][2], bb[4][2];
#pragma unroll
    for (int kk = 0; kk < 2; ++kk) {
#pragma unroll
      for (int mi = 0; mi < 2; ++mi) af[mi][kk] = *(const short8*)(base + aoff[mi][kk]);
#pragma unroll
      for (int ni = 0; ni < 4; ++ni) bb[ni][kk] = *(const short8*)(base + boff[ni][kk]);
    }
#pragma unroll
    for (int kk = 0; kk < 2; ++kk)
#pragma unroll
      for (int mi = 0; mi < 2; ++mi)
#pragma unroll
        for (int ni = 0; ni < 4; ++ni)
          acc[mi][ni] = __builtin_amdgcn_mfma_f32_16x16x32_bf16(af[mi][kk], bb[ni][kk], acc[mi][ni], 0, 0, 0);
  }

  const int hb4 = (n0 + wn * 64) >> 2;
  const int hg = hb4 + fr;
  const float b0 = bias1[n0 + wn * 64 + fr];
  const float b1 = bias1[n0 + wn * 64 + 16 + fr];
  const float b2 = bias1[n0 + wn * 64 + 32 + fr];
  const float b3 = bias1[n0 + wn * 64 + 48 + fr];
  float hsv[2][4];
#pragma unroll
  for (int mi = 0; mi < 2; ++mi)
#pragma unroll
    for (int r = 0; r < 4; ++r) {
      int row = m0 + wm * 32 + mi * 16 + fq * 4 + r;
      size_t sidx = (size_t)row * NH + hg;
      float iv = acc[mi][0][r] + b0;
      float fv = acc[mi][1][r] + b1;
      float gv = acc[mi][2][r] + b2;
      float ov = acc[mi][3][r] + b3;
      float cp = cs1[sidx];
      float c2 = sigf(fv) * cp + sigf(iv) * tanhf(gv);
      float hvv = sigf(ov) * tanhf(c2);
      cs1[sidx] = c2;
      h1_out[(size_t)row * NH + swz(row, hg)] = f2bf(hvv);
      hsv[mi][r] = hvv;
    }

  // partial cc = h1_tile @ outW^T via transpose-MFMA; per (n_blk, wn) slice
  {
    u16* ts = SM + w * 512;  // per-wave 16x32 scratch in buf0 A-area (last chunk used buf1)
    *(short4v*)(ts + (lane >> 2) * 32 + 16 + (lane & 3) * 4) = short4v{0, 0, 0, 0};
    short8 afr = {0, 0, 0, 0, 0, 0, 0, 0};
    if (fq < 2) afr = *(const short8*)(a.owbf + (size_t)fr * NH + hb4 + fq * 8);
    float* pout = a.partial + ((size_t)(dir * 64 + n_blk * 2 + wn) * 512) * 16;
#pragma unroll
    for (int mi = 0; mi < 2; ++mi) {
#pragma unroll
      for (int r = 0; r < 4; ++r)
        *(ts + (fq * 4 + r) * 32 + fr) = f2bf(hsv[mi][r]);
      asm volatile("s_waitcnt lgkmcnt(0)" ::: "memory");
      __builtin_amdgcn_sched_barrier(0);
      short8 bfr2 = *(const short8*)(ts + fr * 32 + fq * 8);
      f32x4 pz = {0.f, 0.f, 0.f, 0.f};
      pz = __builtin_amdgcn_mfma_f32_16x16x32_bf16(afr, bfr2, pz, 0, 0, 0);
      int row = m0 + wm * 32 + mi * 16 + fr;
      float4 st = {pz[0], pz[1], pz[2], pz[3]};
      *(float4*)(pout + (size_t)row * 16 + fq * 4) = st;
      asm volatile("s_waitcnt lgkmcnt(0)" ::: "memory");
      __builtin_amdgcn_sched_barrier(0);
    }
  }
}

// ================= per-step kernels =================
__global__ __launch_bounds__(256) void k_g0(StepCtx a, int t) {
  __shared__ u16 SM[3 * LDSBUF];
  phase_g0(SM, a, blockIdx.z, blockIdx.y, blockIdx.x, t, t & 1);
}
__global__ __launch_bounds__(256) void k_g1(StepCtx a, int t) {
  __shared__ u16 SM[3 * LDSBUF];
  phase_g1(SM, a, blockIdx.z, blockIdx.y, blockIdx.x, t, t & 1);
}

// ---------------- final outputs ----------------
__global__ void k_final(const u16* hf1, const u16* hb1, const float* values,
                        const float* masks, float* out) {
  int idx = blockIdx.x * 256 + threadIdx.x;
  int b = idx >> 10, j = idx & 1023;
  float hf = bf2f(hf1[(size_t)b * NH + swz(b, j)]);
  int jr = NH - 1 - j;
  float hb = bf2f(hb1[(size_t)b * NH + swz(b, jr)]);
  float hv = 0.5f * (hf + hb);
  float m = masks[idx];
  out[idx] = hv;
  out[524288 + idx] = hv;
  out[1048576 + idx] = hv * (1.f - m) + values[idx] * m;
}

extern "C" void kernel_launch(void* const* d_in, const int* in_sizes, int n_in,
                              void* d_out, int out_size, void* d_ws, size_t ws_size,
                              hipStream_t stream) {
  const float* values  = (const float*)d_in[0];
  const float* masks   = (const float*)d_in[1];
  const float* fw_Wih0 = (const float*)d_in[2];
  const float* fw_Whh0 = (const float*)d_in[3];
  const float* fw_bih0 = (const float*)d_in[4];
  const float* fw_bhh0 = (const float*)d_in[5];
  const float* fw_Wih1 = (const float*)d_in[6];
  const float* fw_Whh1 = (const float*)d_in[7];
  const float* fw_bih1 = (const float*)d_in[8];
  const float* fw_bhh1 = (const float*)d_in[9];
  const float* bw_Wih0 = (const float*)d_in[10];
  const float* bw_Whh0 = (const float*)d_in[11];
  const float* bw_bih0 = (const float*)d_in[12];
  const float* bw_bhh0 = (const float*)d_in[13];
  const float* bw_Wih1 = (const float*)d_in[14];
  const float* bw_Whh1 = (const float*)d_in[15];
  const float* bw_bih1 = (const float*)d_in[16];
  const float* bw_bhh1 = (const float*)d_in[17];
  const float* out_W   = (const float*)d_in[18];
  const float* out_b   = (const float*)d_in[19];

  char* ws = (char*)d_ws;
  u16* wbig    = (u16*)ws;                    // 6 x 4M u16
  u16* wih0p   = (u16*)(ws + 50331648);       // 2 x 4096x64
  float* biasb = (float*)(ws + 51380224);     // 4 x 4096
  u16* owbf    = (u16*)(ws + 51445760);       // 16x1024 bf16
  float* c0    = (float*)(ws + 51478528);     // 2 x 512x1024 f32
  float* c1    = (float*)(ws + 55672832);
  u16* h0bf    = (u16*)(ws + 59867136);       // [dir][pp] x 512x1024 bf16 swizzled
  u16* h1bf    = (u16*)(ws + 64061440);
  float* partial = (float*)(ws + 68255744);   // [dir][64][512][16] f32 = 4 MB
  if (ws_size < 72450048) return;

  k_prep_big<<<4096, 256, 0, stream>>>(fw_Whh0, fw_Wih1, fw_Whh1, bw_Whh0, bw_Wih1, bw_Whh1, wbig);
  k_prep_small<<<2176, 256, 0, stream>>>(fw_Wih0, bw_Wih0, fw_bih0, fw_bhh0, fw_bih1, fw_bhh1,
                                         bw_bih0, bw_bhh0, bw_bih1, bw_bhh1, out_W,
                                         wih0p, biasb, owbf);
  k_init<<<4096, 256, 0, stream>>>(fw_bih1, fw_bhh1, bw_bih1, bw_bhh1, c0, c1, h0bf, h1bf);
  hipMemsetAsync(partial, 0, 4194304, stream);
  k_cc0<<<dim3(128, 2), 256, 0, stream>>>(h1bf, h1bf + (size_t)2 * 524288, out_W, partial);

  StepCtx sc;
  sc.h0bf = h0bf; sc.h1bf = h1bf;
  sc.wbig = wbig; sc.wih0p = wih0p;
  sc.biasb = biasb; sc.c0 = c0; sc.c1 = c1;
  sc.partial = partial;
  sc.values = values; sc.masks = masks; sc.outb = out_b;
  sc.owbf = owbf;

  for (int t = 0; t < NT; ++t) {
    k_g0<<<dim3(32, 8, 2), 256, 0, stream>>>(sc, t);
    k_g1<<<dim3(32, 8, 2), 256, 0, stream>>>(sc, t);
  }

  // after t=63: p=1, final h1 in buffer (1-p)=0
  k_final<<<2048, 256, 0, stream>>>(h1bf, h1bf + (size_t)2 * 524288, values, masks, (float*)d_out);
}